// Round 25
// baseline (351.658 us; speedup 1.0000x reference)
//
#include <hip/hip_runtime.h>
#include <hip/hip_bf16.h>
#include <math.h>

#define B_ 4
#define L_ 1024
#define DM 512
#define NH 8
#define HD 64
#define DFF 2048
#define KS 35
#define QS 1536   // packed QKV row stride
#define CH 128    // attention key chunk
#define NCH (L_/CH)
#define VSEG 16   // V-mean segments per head

typedef __attribute__((ext_vector_type(8))) short bf16x8;
typedef __attribute__((ext_vector_type(4))) float f32x4;

__device__ inline ushort f2b(float f){
  __hip_bfloat16 h = __float2bfloat16(f);
  return *reinterpret_cast<ushort*>(&h);
}
__device__ inline float b2f(ushort u){
  union { unsigned int i; float f; } x; x.i = ((unsigned int)u) << 16; return x.f;
}
__device__ inline float gelu_exact(float x){
  return 0.5f*x*(1.0f+erff(x*0.7071067811865476f));
}

#define GLOAD16(g, l) __builtin_amdgcn_global_load_lds( \
    (const __attribute__((address_space(1))) void*)(g), \
    (__attribute__((address_space(3))) void*)(l), 16, 0, 0)

// ---------------- FUSED prologue: embed + bcat + all weight converts -----------------
// grid 10252 x 256 thr:
//   [0,4096)        embed (2 cols/thread)
//   [4096,4108)     bcat
//   [4108,5644)     wconv QKV   (16x16x6 flattened)
//   [5644,6156)     wconv Wo    (16x16x2)
//   [6156,8204)     wconv W1    (64x16x2)
//   [8204,10252)    wconv W2    (16x64x2)
__global__ __launch_bounds__(256) void prologue_kernel(
    const float* __restrict__ src, const float* __restrict__ Wemb,
    const float* __restrict__ bemb, ushort* __restrict__ Xt,
    const float* __restrict__ Wq, const float* __restrict__ Wk,
    const float* __restrict__ Wv, ushort* __restrict__ Wqkvt,
    const float* __restrict__ Wo, ushort* __restrict__ Wot,
    const float* __restrict__ W1, ushort* __restrict__ W1t,
    const float* __restrict__ W2, ushort* __restrict__ W2t,
    const float* __restrict__ bq, const float* __restrict__ bk,
    const float* __restrict__ bv, float* __restrict__ bqkv)
{
  __shared__ float tile[32][33];
  int bid = blockIdx.x, t = threadIdx.x;
  if (bid < 4096) {
    // ---- embed: one row, 2 columns per thread ----
    int row = bid, l = row & (L_-1);
    if (t < 32) tile[0][t] = src[row*32 + t];
    __syncthreads();
    #pragma unroll
    for (int half = 0; half < 2; half++) {
      int c = t + half*256;
      float acc = bemb[c];
      #pragma unroll
      for (int k = 0; k < 32; k++) acc += tile[0][k]*Wemb[k*DM + c];
      int i2 = c & ~1;
      float freq = expf((float)i2 * (-9.210340371976184f/512.0f));
      float ang = (float)l * freq;
      acc += (c & 1) ? cosf(ang) : sinf(ang);
      Xt[(size_t)row*DM + c] = f2b(acc);
    }
    return;
  }
  bid -= 4096;
  if (bid < 12) {
    int i = bid*256 + t;
    if (i < 2*QS) {
      int ll = i / QS, j = i - ll*QS;
      const float* sp = (j < 512) ? bq : (j < 1024 ? bk : bv);
      bqkv[i] = sp[ll*DM + (j & 511)];
    }
    return;
  }
  bid -= 12;
  // ---- weight convert+transpose: pick source/dest/shape per flattened block id ----
  const float* Wsrc; ushort* Wdst; int K, N, n0, k0;
  if (bid < 1536) {                        // QKV: 16x16x6
    int bx = bid & 15, by = (bid >> 4) & 15, z = bid >> 8;
    int which = z >> 1, l = z & 1;
    Wsrc = ((which == 0) ? Wq : (which == 1) ? Wk : Wv) + (size_t)l*DM*DM;
    Wdst = Wqkvt + (size_t)l*QS*DM + (size_t)which*512*DM;
    K = DM; N = DM; n0 = bx*32; k0 = by*32;
  } else if (bid < 2048) {                 // Wo: 16x16x2
    int w = bid - 1536;
    int bx = w & 15, by = (w >> 4) & 15, z = w >> 8;
    Wsrc = Wo + (size_t)z*DM*DM; Wdst = Wot + (size_t)z*DM*DM;
    K = DM; N = DM; n0 = bx*32; k0 = by*32;
  } else if (bid < 4096) {                 // W1: 64x16x2
    int w = bid - 2048;
    int bx = w % 64, by = (w / 64) & 15, z = w >> 10;
    Wsrc = W1 + (size_t)z*DM*DFF; Wdst = W1t + (size_t)z*DFF*DM;
    K = DM; N = DFF; n0 = bx*32; k0 = by*32;
  } else {                                 // W2: 16x64x2
    int w = bid - 4096;
    int bx = w & 15, by = (w >> 4) & 63, z = w >> 10;
    Wsrc = W2 + (size_t)z*DFF*DM; Wdst = W2t + (size_t)z*DM*DFF;
    K = DFF; N = DM; n0 = bx*32; k0 = by*32;
  }
  int tx = t & 31, ty = t >> 5;
  #pragma unroll
  for (int i = ty; i < 32; i += 8) tile[i][tx] = Wsrc[(size_t)(k0+i)*N + n0+tx];
  __syncthreads();
  #pragma unroll
  for (int i = ty; i < 32; i += 8) Wdst[(size_t)(n0+i)*K + k0+tx] = f2b(tile[tx][i]);
}

// ---------------- bf16 MFMA GEMM: dbuf, K=64/tile, COUNTED vmcnt (T4), XCD-swizzled --
// MODE 0: f32 out, 1: gelu->bf16 out, 2: +R f32 out, 3: plain bf16 out
template<int BM, int BN, int MODE>
__global__ __launch_bounds__(256) void mfma_gemm(
    const ushort* __restrict__ A, const ushort* __restrict__ Bt,
    const float* __restrict__ bias, const float* __restrict__ R,
    float* __restrict__ Cf, ushort* __restrict__ Cb,
    int M, int N, int K)
{
  constexpr int MF = BM/32;          // A fragments per wave
  constexpr int NF = BN/32;          // B fragments per wave
  constexpr int AIT = BM*4/256;      // staging iters per K=32 sub-tile
  constexpr int BIT = BN*4/256;
  constexpr int LT = (AIT + BIT)*2;  // gload_lds ops per K=64 tile per thread (4/6/8)
  __shared__ __align__(16) ushort As[2][2][BM*32];
  __shared__ __align__(16) ushort Bs[2][2][BN*32];
  const int t = threadIdx.x, lane = t & 63, w = t >> 6, wr = w >> 1, wc = w & 1;

  // XCD-chunked bijective swizzle (all grids are multiples of 8)
  const int gx = gridDim.x;
  const int nwg = gx * gridDim.y;
  const int bid = blockIdx.y*gx + blockIdx.x;
  const int swz = (bid & 7)*(nwg >> 3) + (bid >> 3);
  const int row0 = (swz / gx)*BM, col0 = (swz % gx)*BN;

  // staging: linear LDS dest, inverse-swizzled global source (per K=32 sub-tile)
  const ushort* aSrc[AIT]; int aDst[AIT];
  #pragma unroll
  for (int j = 0; j < AIT; j++) {
    int ch = j*256 + t, r = ch >> 2, cc = ch & 3, cs = cc ^ ((r >> 1) & 3);
    aSrc[j] = A + (size_t)(row0 + r)*K + cs*8;
    aDst[j] = ch*16;
  }
  const ushort* bSrc[BIT]; int bDst[BIT];
  #pragma unroll
  for (int j = 0; j < BIT; j++) {
    int ch = j*256 + t, r = ch >> 2, cc = ch & 3, cs = cc ^ ((r >> 1) & 3);
    bSrc[j] = Bt + (size_t)(col0 + r)*K + cs*8;
    bDst[j] = ch*16;
  }
  // fragment read offsets (swizzled, within one sub-tile)
  int aOff[MF], bOff[NF];
  #pragma unroll
  for (int m = 0; m < MF; m++) {
    int r = wr*(BM/2) + m*16 + (lane & 15);
    aOff[m] = r*64 + (((lane >> 4)*16) ^ (((r >> 1) & 3) << 4));
  }
  #pragma unroll
  for (int n = 0; n < NF; n++) {
    int r = wc*(BN/2) + n*16 + (lane & 15);
    bOff[n] = r*64 + (((lane >> 4)*16) ^ (((r >> 1) & 3) << 4));
  }
  f32x4 zero = {0.f, 0.f, 0.f, 0.f};
  f32x4 acc[MF][NF];
  #pragma unroll
  for (int m = 0; m < MF; m++)
    #pragma unroll
    for (int n = 0; n < NF; n++) acc[m][n] = zero;

#define STAGE_TILE(kt, buf) do { \
    _Pragma("unroll") \
    for (int j = 0; j < AIT; j++) GLOAD16(aSrc[j] + (kt),      (char*)As[buf][0] + aDst[j]); \
    _Pragma("unroll") \
    for (int j = 0; j < AIT; j++) GLOAD16(aSrc[j] + (kt) + 32, (char*)As[buf][1] + aDst[j]); \
    _Pragma("unroll") \
    for (int j = 0; j < BIT; j++) GLOAD16(bSrc[j] + (kt),      (char*)Bs[buf][0] + bDst[j]); \
    _Pragma("unroll") \
    for (int j = 0; j < BIT; j++) GLOAD16(bSrc[j] + (kt) + 32, (char*)Bs[buf][1] + bDst[j]); \
  } while (0)

  const int nk = K >> 6;             // K/64, always >= 8 here
  // prologue: 2-deep prefetch — T0 -> buf0, T1 -> buf1
  STAGE_TILE(0, 0);
  STAGE_TILE(64, 1);

  for (int ki = 0; ki < nk; ki++) {
    const int cur = ki & 1;
    // wait for tile ki's loads; tile ki+1's LT loads may remain in flight (never 0 mid-loop)
    if (ki + 1 < nk) {
      if constexpr (LT == 8)      asm volatile("s_waitcnt vmcnt(8)" ::: "memory");
      else if constexpr (LT == 6) asm volatile("s_waitcnt vmcnt(6)" ::: "memory");
      else                        asm volatile("s_waitcnt vmcnt(4)" ::: "memory");
    } else {
      asm volatile("s_waitcnt vmcnt(0)" ::: "memory");
    }
    __builtin_amdgcn_sched_barrier(0);
    __builtin_amdgcn_s_barrier();      // all waves have tile ki resident
    #pragma unroll
    for (int s = 0; s < 2; s++) {      // two K=32 sub-steps, same accumulation order
      bf16x8 af[MF], bfr[NF];
      #pragma unroll
      for (int m = 0; m < MF; m++) af[m] = *(const bf16x8*)((const char*)As[cur][s] + aOff[m]);
      #pragma unroll
      for (int n = 0; n < NF; n++) bfr[n] = *(const bf16x8*)((const char*)Bs[cur][s] + bOff[n]);
      #pragma unroll
      for (int m = 0; m < MF; m++)
        #pragma unroll
        for (int n = 0; n < NF; n++)
          acc[m][n] = __builtin_amdgcn_mfma_f32_16x16x32_bf16(af[m], bfr[n], acc[m][n], 0, 0, 0);
    }
    __builtin_amdgcn_s_barrier();      // all waves done reading buf[cur]
    if (ki + 2 < nk) STAGE_TILE((ki + 2) << 6, cur);   // refill the just-read buffer
  }
#undef STAGE_TILE

  #pragma unroll
  for (int m = 0; m < MF; m++) {
    int rb = row0 + wr*(BM/2) + m*16 + ((lane >> 4) << 2);
    #pragma unroll
    for (int n = 0; n < NF; n++) {
      int c = col0 + wc*(BN/2) + n*16 + (lane & 15);
      float bv = bias[c];
      #pragma unroll
      for (int j = 0; j < 4; j++) {
        size_t idx = (size_t)(rb + j)*N + c;
        float v = acc[m][n][j] + bv;
        if (MODE == 1)      Cb[idx] = f2b(gelu_exact(v));
        else if (MODE == 2) Cf[idx] = v + R[idx];
        else if (MODE == 3) Cb[idx] = f2b(v);
        else                Cf[idx] = v;
      }
    }
  }
}

// ---------------- FUSED: vmean_part (bid<512) + qksample (bid>=512), 64 thr ----------
__global__ __launch_bounds__(64) void qkvm_kernel(const ushort* __restrict__ QKVb,
    const int* __restrict__ idx_s, float* __restrict__ Msc, float* __restrict__ VmeanP)
{
  int bid = blockIdx.x;
  if (bid < 512) {
    // ---- vmean_part body ----
    int gid = bid;
    int seg = gid & (VSEG-1), bh = gid >> 4;
    int h = bh & 7, b = bh >> 3;
    int e = threadIdx.x;
    const ushort* Vb = QKVb + 1024 + h*HD + ((size_t)(b*L_ + seg*(L_/VSEG)))*QS;
    float s = 0.f;
    for (int l0 = 0; l0 < L_/VSEG; l0 += 8) {
      float vv[8];
      #pragma unroll
      for (int j = 0; j < 8; j++) vv[j] = b2f(Vb[(size_t)(l0+j)*QS + e]);
      #pragma unroll
      for (int j = 0; j < 8; j++) s += vv[j];
    }
    VmeanP[gid*HD + e] = s;
    return;
  }
  // ---- qksample body ----
  int gid = bid - 512;               // (b*8+h)*1024 + i
  int i = gid & (L_-1), h = (gid >> 10) & 7, b = gid >> 13;
  int t = threadIdx.x;
  int j4 = t >> 2, e4 = t & 3;       // lane = j4*4 + e4
  const ushort* Qrow = QKVb + ((size_t)(b*L_ + i))*QS + h*HD + e4*16;
  bf16x8 qa = *(const bf16x8*)(Qrow);
  bf16x8 qb = *(const bf16x8*)(Qrow + 8);
  float q[16];
  #pragma unroll
  for (int x = 0; x < 8; x++) { q[x] = b2f((ushort)qa[x]); q[8+x] = b2f((ushort)qb[x]); }
  const ushort* Kbase = QKVb + 512 + h*HD + (size_t)b*L_*QS + e4*16;
  const int* idq = idx_s + i*KS;
  float mx = -3.4e38f, sm = 0.f;
  #pragma unroll
  for (int p = 0; p < 3; p++) {
    int j = p*16 + j4;
    int jc = (j < KS) ? j : 0;       // inactive lanes redo j=0 (result discarded)
    int s = idq[jc];
    const ushort* Kr = Kbase + (size_t)s*QS;
    bf16x8 ka = *(const bf16x8*)(Kr);
    bf16x8 kb = *(const bf16x8*)(Kr + 8);
    float d = 0.f;
    #pragma unroll
    for (int x = 0; x < 8; x++) d += q[x]   * b2f((ushort)ka[x]);
    #pragma unroll
    for (int x = 0; x < 8; x++) d += q[8+x] * b2f((ushort)kb[x]);
    d += __shfl_xor(d, 1);
    d += __shfl_xor(d, 2);
    if (j < KS && e4 == 0) { mx = fmaxf(mx, d); sm += d; }
  }
  #pragma unroll
  for (int off = 4; off < 64; off <<= 1) {
    mx = fmaxf(mx, __shfl_xor(mx, off));
    sm += __shfl_xor(sm, off);
  }
  if (t == 0) Msc[gid] = mx - sm*(1.0f/KS);
}

// ---------------- FUSED: topk (bid<32) + vmean_merge (bid>=32), 64 thr ---------------
__global__ __launch_bounds__(64) void topk_vm_kernel(const float* __restrict__ Msc,
    int* __restrict__ idx_top, const float* __restrict__ VmeanP, float* __restrict__ Vmean)
{
  int bid = blockIdx.x, t = threadIdx.x;
  if (bid >= 32) {
    // ---- vmean_merge body ----
    int bh = bid - 32, e = t;
    float s = 0.f;
    #pragma unroll
    for (int seg = 0; seg < VSEG; seg++) s += VmeanP[(bh*VSEG + seg)*HD + e];
    Vmean[bh*HD + e] = s * (1.f/L_);
    return;
  }
  // ---- topk body (register-resident, no LDS) ----
  int bh = bid;
  float v[16];
  #pragma unroll
  for (int r = 0; r < 16; r++) v[r] = Msc[(size_t)bh*L_ + r*64 + t];
  for (int sel = 0; sel < KS; sel++) {
    float bv = -3.4e38f; int br = 0;
    #pragma unroll
    for (int r = 0; r < 16; r++) {
      bool gt = v[r] > bv;
      bv = gt ? v[r] : bv;
      br = gt ? r : br;
    }
    int bi = br*64 + t;
    #pragma unroll
    for (int off = 32; off; off >>= 1) {
      float ov = __shfl_xor(bv, off); int oi = __shfl_xor(bi, off);
      if (ov > bv || (ov == bv && oi < bi)) { bv = ov; bi = oi; }
    }
    if (t == 0) idx_top[bh*KS + sel] = bi;
    if ((bi & 63) == t) v[bi >> 6] = -3.4e38f;
  }
}

// ---------------- FUSED: attn_part (bid<1024) + ctxfill (bid>=1024), 256 thr ---------
__global__ __launch_bounds__(256) void attnpart_ctx_kernel(const ushort* __restrict__ QKVb,
    const int* __restrict__ idx_top, const float* __restrict__ Vmean, ushort* __restrict__ CTXb,
    float* __restrict__ Pacc, float* __restrict__ Pm, float* __restrict__ Pl)
{
  int bid = blockIdx.x;
  int t = threadIdx.x;
  __shared__ float qs[9][68];          // scaled Q rows (padded pitch)
  __shared__ float sc[9][132];         // scores -> exp'd scores
  __shared__ float sm[9], sl[9];
  if (bid >= 1024) {
    // ---- ctxfill body: 2 rows per block ----
    int r0 = (bid - 1024)*2;
    int b = r0 >> 10;
    ushort v0 = f2b(Vmean[b*DM + t]);
    ushort v1 = f2b(Vmean[b*DM + 256 + t]);
    CTXb[(size_t)r0*DM + t] = v0;
    CTXb[(size_t)r0*DM + 256 + t] = v1;
    int r1 = r0 + 1;
    CTXb[(size_t)r1*DM + t] = v0;
    CTXb[(size_t)r1*DM + 256 + t] = v1;
    return;
  }
  // ---- attn_part body ----
  int gid = bid;
  int q = gid & 3, c = (gid >> 2) & 7, bh = gid >> 5;
  int h = bh & 7, b = bh >> 3;
  int chunk = bh*NCH + c;
  int u0 = q*9;
  int NU = (q == 3) ? 8 : 9;

  // load + scale this block's Q rows
  for (int idx = t; idx < NU*64; idx += 256) {
    int ul = idx >> 6, e = idx & 63;
    int qi = idx_top[bh*KS + u0 + ul];
    qs[ul][e] = b2f(QKVb[((size_t)(b*L_ + qi))*QS + h*HD + e]) * 0.125f;
  }
  __syncthreads();

  // scores: thread k = t&127 owns one key; K row in 8 bf16x8 regs (convert inline)
  {
    int k = t & 127, par = t >> 7;
    const ushort* Kr = QKVb + ((size_t)(b*L_ + c*CH + k))*QS + 512 + h*HD;
    bf16x8 kreg[8];
    #pragma unroll
    for (int i8 = 0; i8 < 8; i8++) kreg[i8] = *(const bf16x8*)(Kr + i8*8);
    for (int ul = par; ul < NU; ul += 2) {
      float d = 0.f;
      #pragma unroll
      for (int i8 = 0; i8 < 8; i8++) {
        bf16x8 kv = kreg[i8];
        float4 qa = *(const float4*)&qs[ul][i8*8];
        float4 qb = *(const float4*)&qs[ul][i8*8 + 4];
        d += qa.x*b2f((ushort)kv[0]) + qa.y*b2f((ushort)kv[1])
           + qa.z*b2f((ushort)kv[2]) + qa.w*b2f((ushort)kv[3]);
        d += qb.x*b2f((ushort)kv[4]) + qb.y*b2f((ushort)kv[5])
           + qb.z*b2f((ushort)kv[6]) + qb.w*b2f((ushort)kv[7]);
      }
      sc[ul][k] = d;
    }
  }
  __syncthreads();

  // softmax per ul: 4 threads/row
  {
    int ul = t >> 2, sub = t & 3;
    if (ul < NU) {
      float m = -3.4e38f;
      for (int i = sub; i < 128; i += 4) m = fmaxf(m, sc[ul][i]);
      m = fmaxf(m, __shfl_xor(m, 1));
      m = fmaxf(m, __shfl_xor(m, 2));
      float l = 0.f;
      for (int i = sub; i < 128; i += 4) {
        float ev = expf(sc[ul][i] - m);
        sc[ul][i] = ev;
        l += ev;
      }
      l += __shfl_xor(l, 1);
      l += __shfl_xor(l, 2);
      if (sub == 0) { sm[ul] = m; sl[ul] = l; }
    }
  }
  __syncthreads();

  // partial PV: thread = (ug, e); 8-deep manual load pipeline (ILP)
  {
    int e = t & 63, ug = t >> 6;
    const ushort* Vb = QKVb + 1024 + h*HD + ((size_t)(b*L_ + c*CH))*QS;
    float acc[3] = {0.f, 0.f, 0.f};
    for (int kb0 = 0; kb0 < CH; kb0 += 8) {
      float vv[8];
      #pragma unroll
      for (int j = 0; j < 8; j++) vv[j] = b2f(Vb[(size_t)(kb0 + j)*QS + e]);   // 8 loads in flight
      #pragma unroll
      for (int j = 0; j < 8; j++) {
        #pragma unroll
        for (int iu = 0; iu < 3; iu++) {
          int ul = ug + iu*4;
          if (ul < NU) acc[iu] += sc[ul][kb0 + j] * vv[j];   // sc read is wave-uniform broadcast
        }
      }
    }
    #pragma unroll
    for (int iu = 0; iu < 3; iu++) {
      int ul = ug + iu*4;
      if (ul < NU) Pacc[((size_t)chunk*35 + u0 + ul)*64 + e] = acc[iu];
    }
  }
  if (t < NU) { Pm[chunk*35 + u0 + t] = sm[t]; Pl[chunk*35 + u0 + t] = sl[t]; }
}

// ---------------- phase B: merge partials, scatter bf16 ctx ----------------
__global__ __launch_bounds__(256) void attn_merge_kernel(const float* __restrict__ Pacc,
    const float* __restrict__ Pm, const float* __restrict__ Pl,
    const int* __restrict__ idx_top, ushort* __restrict__ CTXb)
{
  int bh = blockIdx.x;
  int h = bh & 7, b = bh >> 3;
  int t = threadIdx.x;
  __shared__ float m8[NCH*35], l8[NCH*35];
  for (int i = t; i < NCH*35; i += 256) {
    int c = i / 35, u = i - c*35;
    m8[c*35 + u] = Pm[((size_t)bh*NCH + c)*35 + u];
    l8[c*35 + u] = Pl[((size_t)bh*NCH + c)*35 + u];
  }
  __syncthreads();
  int e = t & 63, ug = t >> 6;
  #pragma unroll
  for (int iu = 0; iu < 9; iu++) {
    int u = ug + iu*4;
    if (u >= 35) break;
    float M = -3.4e38f;
    #pragma unroll
    for (int c = 0; c < NCH; c++) M = fmaxf(M, m8[c*35 + u]);
    float Ltot = 0.f, o = 0.f;
    #pragma unroll
    for (int c = 0; c < NCH; c++) {
      float w = expf(m8[c*35 + u] - M);
      Ltot += w * l8[c*35 + u];
      o += w * Pacc[(((size_t)bh*NCH + c)*35 + u)*64 + e];
    }
    int qi = idx_top[bh*KS + u];
    CTXb[((size_t)(b*L_ + qi))*DM + h*HD + e] = f2b(o / Ltot);
  }
}

// ---------------- LayerNorm: wave-per-row, bf16x8 loads, zero LDS/barriers -----------
// grid: M/8 blocks x 512 threads (8 waves = 8 rows per block)
__global__ __launch_bounds__(512) void ln_kernel(const ushort* __restrict__ Xin,
    const ushort* __restrict__ AddB, const float* __restrict__ g, const float* __restrict__ beta,
    ushort* __restrict__ Xout)
{
  int wave = threadIdx.x >> 6, lane = threadIdx.x & 63;
  int row = blockIdx.x*8 + wave;
  size_t base = (size_t)row*DM + lane*8;
  bf16x8 xv = *(const bf16x8*)(Xin + base);
  float v[8];
  #pragma unroll
  for (int j = 0; j < 8; j++) v[j] = b2f((ushort)xv[j]);
  if (AddB) {
    bf16x8 av = *(const bf16x8*)(AddB + base);
    #pragma unroll
    for (int j = 0; j < 8; j++) v[j] += b2f((ushort)av[j]);
  }
  float s = 0.f;
  #pragma unroll
  for (int j = 0; j < 8; j++) s += v[j];
  #pragma unroll
  for (int off = 32; off; off >>= 1) s += __shfl_xor(s, off);
  float mean = s * (1.f/DM);
  float q = 0.f;
  #pragma unroll
  for (int j = 0; j < 8; j++) { float d = v[j] - mean; q += d*d; }
  #pragma unroll
  for (int off = 32; off; off >>= 1) q += __shfl_xor(q, off);
  float sq = sqrtf(q * (1.f/DM) + 1e-5f);
  float4 g0 = *(const float4*)(g + lane*8),  g1v = *(const float4*)(g + lane*8 + 4);
  float4 b0 = *(const float4*)(beta + lane*8), b1v = *(const float4*)(beta + lane*8 + 4);
  float gg[8] = {g0.x,g0.y,g0.z,g0.w,g1v.x,g1v.y,g1v.z,g1v.w};
  float bb[8] = {b0.x,b0.y,b0.z,b0.w,b1v.x,b1v.y,b1v.z,b1v.w};
  bf16x8 ov;
  #pragma unroll
  for (int j = 0; j < 8; j++) ov[j] = (short)f2b((v[j] - mean) / sq * gg[j] + bb[j]);
  *(bf16x8*)(Xout + base) = ov;
}

// ---------------- FUSED final LN + mean pool (no Xt write) ----------------
// grid: 256 blocks x 512 thr; block p = b*64+seg covers 16 rows; wave w -> rows 2w,2w+1
__global__ __launch_bounds__(512) void lnpool_kernel(const ushort* __restrict__ Xin,
    const float* __restrict__ g, const float* __restrict__ beta, float* __restrict__ pooledP)
{
  __shared__ float red2[8][512];
  int p = blockIdx.x;
  int wave = threadIdx.x >> 6, lane = threadIdx.x & 63;
  int b = p >> 6, seg = p & 63;
  int row0 = b*L_ + seg*16 + wave*2;
  float4 g0 = *(const float4*)(g + lane*8),  g1v = *(const float4*)(g + lane*8 + 4);
  float4 b0 = *(const float4*)(beta + lane*8), b1v = *(const float4*)(beta + lane*8 + 4);
  float gg[8] = {g0.x,g0.y,g0.z,g0.w,g1v.x,g1v.y,g1v.z,g1v.w};
  float bb[8] = {b0.x,b0.y,b0.z,b0.w,b1v.x,b1v.y,b1v.z,b1v.w};
  float psum[8] = {0.f,0.f,0.f,0.f,0.f,0.f,0.f,0.f};
  #pragma unroll
  for (int r = 0; r < 2; r++) {
    size_t base = (size_t)(row0 + r)*DM + lane*8;
    bf16x8 xv = *(const bf16x8*)(Xin + base);
    float v[8];
    #pragma unroll
    for (int j = 0; j < 8; j++) v[j] = b2f((ushort)xv[j]);
    float s = 0.f;
    #pragma unroll
    for (int j = 0; j < 8; j++) s += v[j];
    #pragma unroll
    for (int off = 32; off; off >>= 1) s += __shfl_xor(s, off);
    float mean = s * (1.f/DM);
    float q = 0.f;
    #pragma unroll
    for (int j = 0; j < 8; j++) { float d = v[j] - mean; q += d*d; }
    #pragma unroll
    for (int off = 32; off; off >>= 1) q += __shfl_xor(q, off);
    float sq = sqrtf(q * (1.f/DM) + 1e-5f);
    #pragma unroll
    for (int j = 0; j < 8; j++) psum[j] += (v[j] - mean) / sq * gg[j] + bb[j];
  }
  #pragma unroll
  for (int j = 0; j < 8; j++) red2[wave][lane*8 + j] = psum[j];
  __syncthreads();
  int t = threadIdx.x;
  float s = 0.f;
  #pragma unroll
  for (int w = 0; w < 8; w++) s += red2[w][t];
  pooledP[(size_t)p*DM + t] = s;
}

__global__ __launch_bounds__(64) void cls_kernel(const float* __restrict__ pooledP,
    const float* __restrict__ Wc, const float* __restrict__ bc, float* __restrict__ out)
{
  int o = blockIdx.x;
  int b = o/10, c = o%10, t = threadIdx.x;
  float s = 0.f;
  for (int d = t; d < DM; d += 64) {
    float pa = 0.f;
    #pragma unroll
    for (int s8 = 0; s8 < 64; s8 += 8) {
      float vv[8];
      #pragma unroll
      for (int j = 0; j < 8; j++) vv[j] = pooledP[(size_t)(b*64 + s8 + j)*DM + d];
      #pragma unroll
      for (int j = 0; j < 8; j++) pa += vv[j];
    }
    s += pa * (1.f/L_) * Wc[d*10 + c];
  }
  #pragma unroll
  for (int off = 32; off; off >>= 1) s += __shfl_xor(s, off);
  if (t == 0) out[o] = bc[c] + s;
}

extern "C" void kernel_launch(void* const* d_in, const int* in_sizes, int n_in,
                              void* d_out, int out_size, void* d_ws, size_t ws_size,
                              hipStream_t stream)
{
  const float* src   = (const float*)d_in[0];
  const int*   idxs  = (const int*)d_in[1];
  const float* Wemb  = (const float*)d_in[2];
  const float* bemb  = (const float*)d_in[3];
  const float* Wq    = (const float*)d_in[4];
  const float* bq    = (const float*)d_in[5];
  const float* Wk    = (const float*)d_in[6];
  const float* bk    = (const float*)d_in[7];
  const float* Wv    = (const float*)d_in[8];
  const float* bv    = (const float*)d_in[9];
  const float* Wo    = (const float*)d_in[10];
  const float* bo    = (const float*)d_in[11];
  const float* g1    = (const float*)d_in[12];
  const float* beta1 = (const float*)d_in[13];
  const float* W1    = (const float*)d_in[14];
  const float* bf1   = (const float*)d_in[15];
  const float* W2    = (const float*)d_in[16];
  const float* bf2   = (const float*)d_in[17];
  const float* g2    = (const float*)d_in[18];
  const float* beta2 = (const float*)d_in[19];
  const float* gf    = (const float*)d_in[20];
  const float* betaf = (const float*)d_in[21];
  const float* Wc    = (const float*)d_in[22];
  const float* bc    = (const float*)d_in[23];
  float* out = (float*)d_out;

  float* wsf = (float*)d_ws;
  // attention scratch in [0, 2097152); pooledP reuses it AFTER the layers (Pacc dead)
  float*  Pacc  = wsf;                              // 573,440 fl
  float*  VmeanP = wsf + 573440;                    // 32,768 fl (ends 606208 < 2097152)
  float*  pooledP = wsf + 606208;                   // 131,072 fl (ends 737280; used post-layers)
  ushort* Xt    = (ushort*)(wsf + 2097152);         // bf16 trunk: [2097152, 3145728)
  ushort* CTXb  = (ushort*)(wsf + 3145728);         // [3145728, 4194304)
  ushort* QKVb  = (ushort*)(wsf + 4194304);         // bf16 QKV: [4194304, 7340032) fl
  ushort* Ob    = (ushort*)(wsf + 7340032);         // bf16 Wo out: [7340032, 8388608) fl
  ushort* H     = (ushort*)(wsf + 4194304);         // FFN hidden bf16 (QKVb+Ob dead by FFN1)
  ushort* Yb    = (ushort*)(wsf + 8388608);         // bf16 FFN2 out: [8388608, 9437184) fl
  ushort* Wqkvt = (ushort*)(wsf + 10485760);        // 786,432 fl
  ushort* Wot   = (ushort*)(wsf + 11272192);        // 262,144 fl
  ushort* W1t   = (ushort*)(wsf + 11534336);        // 1,048,576 fl
  ushort* W2t   = (ushort*)(wsf + 12582912);        // 1,048,576 fl
  float*  bqkv  = wsf + 13631488;                   // 3,072
  float*  Msc   = wsf + 13634560;                   // 32,768 (dead after topk)
  float*  Pm    = wsf + 13634560;                   // alias Msc: 8,960
  float*  Pl    = wsf + 13634560 + 8960;            // alias Msc: 8,960
  float*  Vmean = wsf + 13667328;                   // 2,048
  int*    idx_top = (int*)(wsf + 13685760);         // 1,120

  // FUSED prologue: embed + bcat + all weight converts (one dispatch)
  prologue_kernel<<<10252, 256, 0, stream>>>(
      src, Wemb, bemb, Xt, Wq, Wk, Wv, Wqkvt, Wo, Wot, W1, W1t, W2, W2t,
      bq, bk, bv, bqkv);

  const int M = B_ * L_; // 4096
  for (int l = 0; l < 2; l++) {
    const size_t vo = (size_t)l*DM;
    // QKV: [4096,512] x [512,1536] -> bf16 out, 12x32 = 384 blocks (128x128 tiles)
    mfma_gemm<128,128,3><<<dim3(QS/128, M/128), 256, 0, stream>>>(
        Xt, Wqkvt + (size_t)l*QS*DM, bqkv + (size_t)l*QS, nullptr, nullptr, QKVb, M, QS, DM);
    // fused: vmean_part (512) + qksample (32768)
    qkvm_kernel<<<512 + B_*NH*L_, 64, 0, stream>>>(QKVb, idxs + (size_t)l*L_*KS, Msc, VmeanP);
    // fused: topk (32) + vmean_merge (32)
    topk_vm_kernel<<<64, 64, 0, stream>>>(Msc, idx_top, VmeanP, Vmean);
    // fused: attn_part (1024) + ctxfill (2048, 2 rows/block)
    attnpart_ctx_kernel<<<1024 + M/2, 256, 0, stream>>>(QKVb, idx_top, Vmean, CTXb, Pacc, Pm, Pl);
    attn_merge_kernel<<<B_*NH, 256, 0, stream>>>(Pacc, Pm, Pl, idx_top, CTXb);
    // Wo: [4096,512] x [512,512] -> bf16 delta Ob (residual added in ln1)
    mfma_gemm<64,64,3><<<dim3(DM/64, M/64), 256, 0, stream>>>(
        CTXb, Wot + (size_t)l*DM*DM, bo + vo, nullptr, nullptr, Ob, M, DM, DM);
    ln_kernel<<<M/8, 512, 0, stream>>>(Xt, Ob, g1 + vo, beta1 + vo, Xt);
    // FFN1: [4096,512] x [512,2048] -> gelu bf16, 16x32 = 512 blocks (128x128 tiles)
    mfma_gemm<128,128,1><<<dim3(DFF/128, M/128), 256, 0, stream>>>(
        Xt, W1t + (size_t)l*DFF*DM, bf1 + (size_t)l*DFF, nullptr, nullptr, H, M, DFF, DM);
    // FFN2: [4096,2048] x [2048,512] -> bf16 delta Yb (residual added in ln2)
    mfma_gemm<64,64,3><<<dim3(DM/64, M/64), 256, 0, stream>>>(
        H, W2t + (size_t)l*DM*DFF, bf2 + vo, nullptr, nullptr, Yb, M, DM, DFF);
    ln_kernel<<<M/8, 512, 0, stream>>>(Xt, Yb, g2 + vo, beta2 + vo, Xt);
  }
  // FUSED final LN + mean pool (no trunk write), then classifier
  lnpool_kernel<<<256, 512, 0, stream>>>(Xt, gf, betaf, pooledP);
  cls_kernel<<<40, 64, 0, stream>>>(pooledP, Wc, bc, out);
}